// Round 2
// baseline (315.300 us; speedup 1.0000x reference)
//
#include <hip/hip_runtime.h>

// FP8 E4M3 bit-level multiplier — latency-optimized.
// Each thread owns KPT float4s (half bit-groups), block-strided so every
// global load/store instruction is lane-unit-stride 16B. All 2*KPT loads are
// issued up front (8 outstanding per wave). Lane pairs (2k,2k+1) exchange
// compacted nibbles via DPP quad_perm [1,0,3,2] — a single VALU op, no LDS,
// no lgkmcnt in the dependent chain. Stores are nontemporal (output is never
// re-read; keeps a/b resident in L2/L3 across bench iterations).

#define BIAS 7
#define KPT 4  // float4 half-groups per thread

typedef float vfloat4 __attribute__((ext_vector_type(4)));  // native vec for nontemporal builtin

__device__ __forceinline__ int rne_rshift(int M, int sh) {
    // round-to-nearest-even right shift of non-negative M by sh >= 0
    int q = M >> sh;
    int rem = M - (q << sh);
    int half = (1 << sh) >> 1;           // 2^(sh-1), 0 when sh==0
    int up = ((rem > half) | ((rem == half) & (q & 1))) & (sh > 0);
    return q + up;
}

__device__ __forceinline__ int fp8_mul_byte(int a8, int b8) {
    int sa = a8 >> 7,        sb_ = b8 >> 7;
    int ea = (a8 >> 3) & 15, eb = (b8 >> 3) & 15;
    int ma = a8 & 7,         mb = b8 & 7;

    int sig_a = (ea == 0) ? ma : (ma + 8);
    int sig_b = (eb == 0) ? mb : (mb + 8);
    int exa = ((ea == 0) ? 1 : ea) - BIAS;
    int exb = ((eb == 0) ? 1 : eb) - BIAS;

    int M = sig_a * sig_b;              // exact product, <= 225
    int E = exa + exb - 6;              // value = M * 2^E

    int p = (M > 0) ? (31 - __clz(M)) : 0;
    int eb_out = E + p + BIAS;

    // normal path (eb_out >= 1): RNE round to 3 mantissa bits
    int sh  = p - 3;
    int shp = (sh > 0) ? sh : 0;
    int lsh = (sh < 0) ? -sh : 0;
    int mant4 = rne_rshift(M, shp) << lsh;   // in [8, 16]
    int carry = mant4 >> 4;
    if (mant4 == 16) mant4 = 8;
    int e_n = eb_out + carry;
    int m_n = mant4 - 8;
    if (e_n >= 16) { e_n = 15; m_n = 7; }    // overflow -> NaN

    // subnormal path (eb_out <= 0): mant = RNE(M * 2^(E+9))
    int t = E + 9;
    int rsh   = (-t < 0) ? 0 : ((-t > 30) ? 30 : -t);
    int lsh_s = (t > 0) ? t : 0;
    int mant_s = rne_rshift(M, rsh) << lsh_s;
    int e_s = (mant_s >= 8) ? 1 : 0;
    int m_s = (mant_s >= 8) ? 0 : mant_s;

    int is_sub = (eb_out <= 0);
    int e_o = is_sub ? e_s : e_n;
    int m_o = is_sub ? m_s : m_n;
    if (M == 0) { e_o = 0; m_o = 0; }
    int s_o = sa ^ sb_;
    return (s_o << 7) | (e_o << 3) | m_o;
}

// inputs are exactly 0.0f (0x00000000) or 1.0f (0x3F800000): bit 23 is the bit.
// packs a-nibble into bits 3..0, b-nibble into bits 7..4.
__device__ __forceinline__ int compact_own(uint4 av, uint4 bv) {
    return (int)(((av.x >> 20) & 8u)   | ((av.y >> 21) & 4u)  |
                 ((av.z >> 22) & 2u)   | ((av.w >> 23) & 1u)  |
                 ((bv.x >> 16) & 128u) | ((bv.y >> 17) & 64u) |
                 ((bv.z >> 18) & 32u)  | ((bv.w >> 19) & 16u));
}

__device__ __forceinline__ void compute_store(int own, int odd, int sbit,
                                              vfloat4* __restrict__ dst) {
    // DPP quad_perm [1,0,3,2] == swap with lane^1. ctrl=0xB1, full masks.
    int pp = __builtin_amdgcn_update_dpp(0, own, 0xB1, 0xF, 0xF, true);

    // even lane holds [s,e3,e2,e1] (high nibble of code), odd holds [e0,m2,m1,m0]
    int a8 = odd ? (((pp  & 0xF) << 4)        |  (own & 0xF))
                 : (((own & 0xF) << 4)        |  (pp  & 0xF));
    int b8 = odd ? ((((pp  >> 4) & 0xF) << 4) | ((own >> 4) & 0xF))
                 : ((((own >> 4) & 0xF) << 4) | ((pp  >> 4) & 0xF));

    int r = fp8_mul_byte(a8, b8);

    vfloat4 o;
    o.x = (float)((r >> sbit)       & 1);
    o.y = (float)((r >> (sbit - 1)) & 1);
    o.z = (float)((r >> (sbit - 2)) & 1);
    o.w = (float)((r >> (sbit - 3)) & 1);
    __builtin_nontemporal_store(o, dst);
}

__global__ void __launch_bounds__(256)
fp8_mul_kernel(const uint4* __restrict__ a, const uint4* __restrict__ b,
               vfloat4* __restrict__ out, int n_vec) {
    const int base = blockIdx.x * (256 * KPT) + threadIdx.x;
    const int odd  = threadIdx.x & 1;           // lane parity == group-half parity
    const int sbit = odd ? 3 : 7;               // which 4 result bits this lane stores

    if (base + 256 * (KPT - 1) < n_vec) {
        // fast path: full tile. Issue all loads first -> 8 outstanding per wave.
        uint4 av[KPT], bv[KPT];
#pragma unroll
        for (int k = 0; k < KPT; ++k) {
            av[k] = a[base + 256 * k];
            bv[k] = b[base + 256 * k];
        }
        int own[KPT];
#pragma unroll
        for (int k = 0; k < KPT; ++k) own[k] = compact_own(av[k], bv[k]);
#pragma unroll
        for (int k = 0; k < KPT; ++k)
            compute_store(own[k], odd, sbit, &out[base + 256 * k]);
    } else {
        // tail: per-element guard. Lane pairs share the same predicate
        // (n_vec is even), so the DPP partner is always active.
        for (int k = 0; k < KPT; ++k) {
            int j = base + 256 * k;
            if (j >= n_vec) continue;
            uint4 av = a[j];
            uint4 bv = b[j];
            compute_store(compact_own(av, bv), odd, sbit, &out[j]);
        }
    }
}

extern "C" void kernel_launch(void* const* d_in, const int* in_sizes, int n_in,
                              void* d_out, int out_size, void* d_ws, size_t ws_size,
                              hipStream_t stream) {
    const uint4* a = (const uint4*)d_in[0];
    const uint4* b = (const uint4*)d_in[1];
    vfloat4* out = (vfloat4*)d_out;
    int n_vec = in_sizes[0] / 4;                 // one float4 (half group) per thread-slot
    int block = 256;
    int grid = (n_vec + block * KPT - 1) / (block * KPT);
    fp8_mul_kernel<<<grid, block, 0, stream>>>(a, b, out, n_vec);
}

// Round 3
// 306.020 us; speedup vs baseline: 1.0303x; 1.0303x over previous
//
#include <hip/hip_runtime.h>

// FP8 E4M3 bit-level multiplier.
// Each thread owns KPT float4s (half bit-groups), block-strided so every
// global load/store instruction is lane-unit-stride 16B. All 2*KPT loads are
// issued up front (8 outstanding per wave). Lane pairs (2k,2k+1) exchange
// compacted nibbles via DPP quad_perm [1,0,3,2] — a single VALU op, no LDS,
// no lgkmcnt in the dependent chain. Stores are PLAIN (cached): Round-2
// showed nontemporal stores regress 103->126us (write-through defeats L2
// write absorption; FETCH_SIZE unchanged so no input-caching benefit).

#define BIAS 7
#define KPT 4  // float4 half-groups per thread

typedef float vfloat4 __attribute__((ext_vector_type(4)));

__device__ __forceinline__ int rne_rshift(int M, int sh) {
    // round-to-nearest-even right shift of non-negative M by sh >= 0
    int q = M >> sh;
    int rem = M - (q << sh);
    int half = (1 << sh) >> 1;           // 2^(sh-1), 0 when sh==0
    int up = ((rem > half) | ((rem == half) & (q & 1))) & (sh > 0);
    return q + up;
}

__device__ __forceinline__ int fp8_mul_byte(int a8, int b8) {
    int sa = a8 >> 7,        sb_ = b8 >> 7;
    int ea = (a8 >> 3) & 15, eb = (b8 >> 3) & 15;
    int ma = a8 & 7,         mb = b8 & 7;

    int sig_a = (ea == 0) ? ma : (ma + 8);
    int sig_b = (eb == 0) ? mb : (mb + 8);
    int exa = ((ea == 0) ? 1 : ea) - BIAS;
    int exb = ((eb == 0) ? 1 : eb) - BIAS;

    int M = sig_a * sig_b;              // exact product, <= 225
    int E = exa + exb - 6;              // value = M * 2^E

    int p = (M > 0) ? (31 - __clz(M)) : 0;
    int eb_out = E + p + BIAS;

    // normal path (eb_out >= 1): RNE round to 3 mantissa bits
    int sh  = p - 3;
    int shp = (sh > 0) ? sh : 0;
    int lsh = (sh < 0) ? -sh : 0;
    int mant4 = rne_rshift(M, shp) << lsh;   // in [8, 16]
    int carry = mant4 >> 4;
    if (mant4 == 16) mant4 = 8;
    int e_n = eb_out + carry;
    int m_n = mant4 - 8;
    if (e_n >= 16) { e_n = 15; m_n = 7; }    // overflow -> NaN

    // subnormal path (eb_out <= 0): mant = RNE(M * 2^(E+9))
    int t = E + 9;
    int rsh   = (-t < 0) ? 0 : ((-t > 30) ? 30 : -t);
    int lsh_s = (t > 0) ? t : 0;
    int mant_s = rne_rshift(M, rsh) << lsh_s;
    int e_s = (mant_s >= 8) ? 1 : 0;
    int m_s = (mant_s >= 8) ? 0 : mant_s;

    int is_sub = (eb_out <= 0);
    int e_o = is_sub ? e_s : e_n;
    int m_o = is_sub ? m_s : m_n;
    if (M == 0) { e_o = 0; m_o = 0; }
    int s_o = sa ^ sb_;
    return (s_o << 7) | (e_o << 3) | m_o;
}

// inputs are exactly 0.0f (0x00000000) or 1.0f (0x3F800000): bit 23 is the bit.
// packs a-nibble into bits 3..0, b-nibble into bits 7..4.
__device__ __forceinline__ int compact_own(uint4 av, uint4 bv) {
    return (int)(((av.x >> 20) & 8u)   | ((av.y >> 21) & 4u)  |
                 ((av.z >> 22) & 2u)   | ((av.w >> 23) & 1u)  |
                 ((bv.x >> 16) & 128u) | ((bv.y >> 17) & 64u) |
                 ((bv.z >> 18) & 32u)  | ((bv.w >> 19) & 16u));
}

__device__ __forceinline__ void compute_store(int own, int odd, int sbit,
                                              vfloat4* __restrict__ dst) {
    // DPP quad_perm [1,0,3,2] == swap with lane^1. ctrl=0xB1, full masks.
    int pp = __builtin_amdgcn_update_dpp(0, own, 0xB1, 0xF, 0xF, true);

    // even lane holds [s,e3,e2,e1] (high nibble of code), odd holds [e0,m2,m1,m0]
    int a8 = odd ? (((pp  & 0xF) << 4)        |  (own & 0xF))
                 : (((own & 0xF) << 4)        |  (pp  & 0xF));
    int b8 = odd ? ((((pp  >> 4) & 0xF) << 4) | ((own >> 4) & 0xF))
                 : ((((own >> 4) & 0xF) << 4) | ((pp  >> 4) & 0xF));

    int r = fp8_mul_byte(a8, b8);

    vfloat4 o;
    o.x = (float)((r >> sbit)       & 1);
    o.y = (float)((r >> (sbit - 1)) & 1);
    o.z = (float)((r >> (sbit - 2)) & 1);
    o.w = (float)((r >> (sbit - 3)) & 1);
    *dst = o;                             // plain cached store
}

__global__ void __launch_bounds__(256)
fp8_mul_kernel(const uint4* __restrict__ a, const uint4* __restrict__ b,
               vfloat4* __restrict__ out, int n_vec) {
    const int base = blockIdx.x * (256 * KPT) + threadIdx.x;
    const int odd  = threadIdx.x & 1;           // lane parity == group-half parity
    const int sbit = odd ? 3 : 7;               // which 4 result bits this lane stores

    if (base + 256 * (KPT - 1) < n_vec) {
        // fast path: full tile. Issue all loads first -> 8 outstanding per wave.
        uint4 av[KPT], bv[KPT];
#pragma unroll
        for (int k = 0; k < KPT; ++k) {
            av[k] = a[base + 256 * k];
            bv[k] = b[base + 256 * k];
        }
        int own[KPT];
#pragma unroll
        for (int k = 0; k < KPT; ++k) own[k] = compact_own(av[k], bv[k]);
#pragma unroll
        for (int k = 0; k < KPT; ++k)
            compute_store(own[k], odd, sbit, &out[base + 256 * k]);
    } else {
        // tail: per-element guard. Lane pairs share the same predicate
        // (n_vec is even), so the DPP partner is always active.
        for (int k = 0; k < KPT; ++k) {
            int j = base + 256 * k;
            if (j >= n_vec) continue;
            uint4 av = a[j];
            uint4 bv = b[j];
            compute_store(compact_own(av, bv), odd, sbit, &out[j]);
        }
    }
}

extern "C" void kernel_launch(void* const* d_in, const int* in_sizes, int n_in,
                              void* d_out, int out_size, void* d_ws, size_t ws_size,
                              hipStream_t stream) {
    const uint4* a = (const uint4*)d_in[0];
    const uint4* b = (const uint4*)d_in[1];
    vfloat4* out = (vfloat4*)d_out;
    int n_vec = in_sizes[0] / 4;                 // one float4 (half group) per thread-slot
    int block = 256;
    int grid = (n_vec + block * KPT - 1) / (block * KPT);
    fp8_mul_kernel<<<grid, block, 0, stream>>>(a, b, out, n_vec);
}